// Round 9
// baseline (292.747 us; speedup 1.0000x reference)
//
#include <hip/hip_runtime.h>
#include <hip/hip_bf16.h>
#include <stdint.h>

typedef __attribute__((ext_vector_type(8))) short s16x8;
typedef __attribute__((ext_vector_type(4))) float f32x4;

__device__ __forceinline__ unsigned short f32_bf16(float f) {
  union { float f; uint32_t u; } v; v.f = f;
  return (unsigned short)((v.u + 0x7FFFu + ((v.u >> 16) & 1u)) >> 16);
}

__device__ __forceinline__ uint32_t pack_bf16(float lo, float hi) {
  __hip_bfloat162 h = __float22bfloat162_rn(float2{lo, hi});
  union { __hip_bfloat162 h; uint32_t u; } u; u.h = h; return u.u;
}

// Exchange 4-row chunks across the four 16-lane groups to build an MFMA
// A-fragment (k = 8*l4 + j) from C-fragment-resident data (lane = row).
__device__ __forceinline__ s16x8 xchg(uint32_t lo0, uint32_t lo1,
                                      uint32_t hi0, uint32_t hi1,
                                      int srcA, int srcB, uint32_t hisel) {
  int a0 = __shfl((int)lo0, srcA), b0 = __shfl((int)hi0, srcA);
  int a1 = __shfl((int)lo1, srcA), b1 = __shfl((int)hi1, srcA);
  int a2 = __shfl((int)lo0, srcB), b2 = __shfl((int)hi0, srcB);
  int a3 = __shfl((int)lo1, srcB), b3 = __shfl((int)hi1, srcB);
  union { uint32_t u[4]; s16x8 v; } r;
  r.u[0] = hisel ? (uint32_t)b0 : (uint32_t)a0;
  r.u[1] = hisel ? (uint32_t)b1 : (uint32_t)a1;
  r.u[2] = hisel ? (uint32_t)b2 : (uint32_t)a2;
  r.u[3] = hisel ? (uint32_t)b3 : (uint32_t)a3;
  return r.v;
}

// ---------------- kernel 1: weights f32 -> bf16 ----------------
__global__ void convert_w(const float* __restrict__ wqkv,
                          const float* __restrict__ wout,
                          unsigned short* __restrict__ o) {
  int i = blockIdx.x * 256 + threadIdx.x;           // 262144 total
  if (i < 768 * 256) o[i] = f32_bf16(wqkv[i]);
  else               o[i] = f32_bf16(wout[i - 768 * 256]);
}

// -------- kernel 2: QKV GEMM (M=131072, N=768, K=256), swapped-C --------
// 128x128 tiles, 4 waves (2x2), BK=64, reg-staged swizzled LDS (the R1-proj
// structure that measured ~800 TF effective). Grid linearized bm-major so
// the 6 bn-blocks sharing one x-tile are temporally adjacent -> x re-reads
// hit L3 instead of HBM. mfma(A=w-frag, B=x-frag) -> C[wcol][tok].
__global__ __launch_bounds__(256) void qkv_gemm(
    const float* __restrict__ x,           // [131072][256] f32
    const unsigned short* __restrict__ wq, // [768][256] bf16
    unsigned short* qk_out,                // d_out: per group 64KB {q 32K | k 32K}
    unsigned short* v_out) {               // ws: per group 32KB v[t64][256]
  __shared__ unsigned short As[128 * 64];
  __shared__ unsigned short Bs[128 * 64];
  const int id = blockIdx.x;
  const int bm = id / 6;           // token tile (bm-major order!)
  const int bn = id - bm * 6;      // weight tile
  const int tid = threadIdx.x;
  const int w = tid >> 6, lane = tid & 63;
  const int l15 = lane & 15, l4 = lane >> 4;
  const int wr = w >> 1, wc = w & 1;

  f32x4 acc[4][4];
#pragma unroll
  for (int mi = 0; mi < 4; ++mi)
#pragma unroll
    for (int ni = 0; ni < 4; ++ni) acc[mi][ni] = (f32x4){0.f, 0.f, 0.f, 0.f};

  const int srow = tid >> 1;
  const int sc0  = (tid & 1) * 32;
  const float* ga = x + (size_t)(bm * 128 + srow) * 256 + sc0;
  const unsigned short* gb = wq + (size_t)(bn * 128 + srow) * 256 + sc0;
  const uint32_t sbyte0 = (uint32_t)(srow * 128 + sc0 * 2);
  const uint32_t ssw = (uint32_t)(srow & 7) << 4;

  for (int kk = 0; kk < 4; ++kk) {
#pragma unroll
    for (int c = 0; c < 32; c += 8) {
      float4 f0 = *(const float4*)(ga + kk * 64 + c);
      float4 f1 = *(const float4*)(ga + kk * 64 + c + 4);
      uint4 vb = *(const uint4*)(gb + kk * 64 + c);
      uint32_t byte = (sbyte0 + c * 2) ^ ssw;
      *(uint4*)((char*)As + byte) =
          make_uint4(pack_bf16(f0.x, f0.y), pack_bf16(f0.z, f0.w),
                     pack_bf16(f1.x, f1.y), pack_bf16(f1.z, f1.w));
      *(uint4*)((char*)Bs + byte) = vb;
    }
    __syncthreads();
#pragma unroll
    for (int k2 = 0; k2 < 2; ++k2) {
      s16x8 af[4], bf[4];
#pragma unroll
      for (int mi = 0; mi < 4; ++mi) {
        int row = wr * 64 + 16 * mi + l15;
        uint32_t byte = (uint32_t)(row * 128 + k2 * 64 + l4 * 16) ^ ((row & 7) << 4);
        af[mi] = *(const s16x8*)((const char*)Bs + byte);   // w rows (A-op)
      }
#pragma unroll
      for (int ni = 0; ni < 4; ++ni) {
        int row = wc * 64 + 16 * ni + l15;
        uint32_t byte = (uint32_t)(row * 128 + k2 * 64 + l4 * 16) ^ ((row & 7) << 4);
        bf[ni] = *(const s16x8*)((const char*)As + byte);   // x rows (B-op)
      }
#pragma unroll
      for (int mi = 0; mi < 4; ++mi)
#pragma unroll
        for (int ni = 0; ni < 4; ++ni)
          acc[mi][ni] = __builtin_amdgcn_mfma_f32_16x16x32_bf16(af[mi], bf[ni], acc[mi][ni], 0, 0, 0);
    }
    __syncthreads();
  }

  // C[wcol][tok]: g = bm*2 + wc, t64 = 16ni + l15, wcol = bn*128+wr*64+16mi+4*l4+r
  const int g = bm * 2 + wc;
  if (bn < 4) {
    char* base = (char*)qk_out + ((size_t)g << 16) + ((bn & 2) ? 32768 : 0);
    const int colb = (bn & 1) * 128 + wr * 64 + 4 * l4;
#pragma unroll
    for (int mi = 0; mi < 4; ++mi)
#pragma unroll
      for (int ni = 0; ni < 4; ++ni) {
        uint2 st = make_uint2(pack_bf16(acc[mi][ni][0], acc[mi][ni][1]),
                              pack_bf16(acc[mi][ni][2], acc[mi][ni][3]));
        *(uint2*)(base + (16 * ni + l15) * 512 + (colb + 16 * mi) * 2) = st;
      }
  } else {
    char* base = (char*)v_out + ((size_t)g << 15);
    const int colb = (bn - 4) * 128 + wr * 64 + 4 * l4;
#pragma unroll
    for (int mi = 0; mi < 4; ++mi)
#pragma unroll
      for (int ni = 0; ni < 4; ++ni) {
        uint2 st = make_uint2(pack_bf16(acc[mi][ni][0], acc[mi][ni][1]),
                              pack_bf16(acc[mi][ni][2], acc[mi][ni][3]));
        *(uint2*)(base + (16 * ni + l15) * 512 + (colb + 16 * mi) * 2) = st;
      }
  }
}

// -------- kernel 3: attention + out-projection, block per group ---------
// (verbatim from R7/R8 — runs at ~90% of its HBM traffic floor)
__global__ __launch_bounds__(512) void attn_proj(
    const unsigned short* qk,              // d_out scratch (aliases out!)
    const unsigned short* __restrict__ v_buf,
    const unsigned short* __restrict__ wo, // [256][256] bf16
    const float* __restrict__ bias,
    float* out) {
  __shared__ unsigned short ot[64 * 256];  // 32 KB attn-out tile, swz rows

  const int g    = blockIdx.x;
  const int tid  = threadIdx.x;
  const int h    = tid >> 6;
  const int lane = tid & 63;
  const int l15  = lane & 15;
  const int l4   = lane >> 4;
  const int      srcA  = l15 + ((lane & 16) << 1);
  const int      srcB  = srcA + 16;
  const uint32_t hisel = (uint32_t)(lane & 32);

  const char* qbase = (const char*)qk + ((size_t)g << 16);
  const int hcolb = (h * 32 + l4 * 8) * 2;

  // ---- load q,k fragments (b128 global) ----
  s16x8 kA[4], qB[4];
#pragma unroll
  for (int mb = 0; mb < 4; ++mb)
    kA[mb] = *(const s16x8*)(qbase + 32768 + (16 * mb + l15) * 512 + hcolb);
#pragma unroll
  for (int nb = 0; nb < 4; ++nb)
    qB[nb] = *(const s16x8*)(qbase + (16 * nb + l15) * 512 + hcolb);

  // ---- load v fragments (scalar u16, B-frag: lane=d col, k=ktok) ----
  s16x8 vB[2][2];
  const char* vb0 = (const char*)v_buf + ((size_t)g << 15);
#pragma unroll
  for (int kk2 = 0; kk2 < 2; ++kk2)
#pragma unroll
    for (int t = 0; t < 2; ++t) {
      union { unsigned short u[8]; s16x8 v; } uv;
      const char* vp = vb0 + (kk2 * 32 + 8 * l4) * 512 + (h * 32 + 16 * t + l15) * 2;
#pragma unroll
      for (int j = 0; j < 8; ++j)
        uv.u[j] = *(const unsigned short*)(vp + j * 512);
      vB[kk2][t] = uv.v;
    }

  // ---- per q-block: energy^T -> softmax -> PV -> LDS store ----
#pragma unroll
  for (int nb = 0; nb < 4; ++nb) {
    f32x4 en[4];
#pragma unroll
    for (int mb = 0; mb < 4; ++mb) {
      en[mb] = (f32x4){0.f, 0.f, 0.f, 0.f};
      en[mb] = __builtin_amdgcn_mfma_f32_16x16x32_bf16(kA[mb], qB[nb], en[mb], 0, 0, 0);
    }
    float mx = en[0][0];
#pragma unroll
    for (int mb = 0; mb < 4; ++mb)
#pragma unroll
      for (int r = 0; r < 4; ++r) mx = fmaxf(mx, en[mb][r]);
    mx = fmaxf(mx, __shfl_xor(mx, 16));
    mx = fmaxf(mx, __shfl_xor(mx, 32));
    float p[4][4];
    float sum = 0.f;
#pragma unroll
    for (int mb = 0; mb < 4; ++mb)
#pragma unroll
      for (int r = 0; r < 4; ++r) {
        float t = __expf((en[mb][r] - mx) * 0.0625f);  // scale 1/sqrt(256)
        p[mb][r] = t;
        sum += t;
      }
    sum += __shfl_xor(sum, 16);
    sum += __shfl_xor(sum, 32);
    float rs = 1.0f / sum;
    uint32_t pk[4][2];
#pragma unroll
    for (int mb = 0; mb < 4; ++mb) {
      pk[mb][0] = pack_bf16(p[mb][0] * rs, p[mb][1] * rs);
      pk[mb][1] = pack_bf16(p[mb][2] * rs, p[mb][3] * rs);
    }
    f32x4 o0 = (f32x4){0.f, 0.f, 0.f, 0.f};
    f32x4 o1 = (f32x4){0.f, 0.f, 0.f, 0.f};
#pragma unroll
    for (int kk2 = 0; kk2 < 2; ++kk2) {
      s16x8 pA = xchg(pk[2 * kk2][0], pk[2 * kk2][1],
                      pk[2 * kk2 + 1][0], pk[2 * kk2 + 1][1], srcA, srcB, hisel);
      o0 = __builtin_amdgcn_mfma_f32_16x16x32_bf16(pA, vB[kk2][0], o0, 0, 0, 0);
      o1 = __builtin_amdgcn_mfma_f32_16x16x32_bf16(pA, vB[kk2][1], o1, 0, 0, 0);
    }
#pragma unroll
    for (int r = 0; r < 4; ++r) {
      int row = 16 * nb + 4 * l4 + r;
      uint32_t rsw = (uint32_t)(row & 7) << 4;
      uint32_t c0 = ((uint32_t)(row * 512 + (h * 32 + l15) * 2)) ^ rsw;
      uint32_t c1 = ((uint32_t)(row * 512 + (h * 32 + 16 + l15) * 2)) ^ rsw;
      *(unsigned short*)((char*)ot + c0) = f32_bf16(o0[r]);
      *(unsigned short*)((char*)ot + c1) = f32_bf16(o1[r]);
    }
  }
  __syncthreads();

  // ---- projection: wave h -> out cols [h*32, h*32+32), swapped C ----
  f32x4 acc2[2][4];
#pragma unroll
  for (int mi = 0; mi < 2; ++mi)
#pragma unroll
    for (int ni = 0; ni < 4; ++ni) acc2[mi][ni] = (f32x4){0.f, 0.f, 0.f, 0.f};

#pragma unroll
  for (int kk = 0; kk < 8; ++kk) {
    s16x8 af[2], bfrag[4];
#pragma unroll
    for (int mi = 0; mi < 2; ++mi)
      af[mi] = *(const s16x8*)(wo + (size_t)(h * 32 + 16 * mi + l15) * 256 + kk * 32 + l4 * 8);
#pragma unroll
    for (int ni = 0; ni < 4; ++ni) {
      uint32_t byte = ((uint32_t)((16 * ni + l15) * 512 + (kk * 32 + l4 * 8) * 2)) ^ ((uint32_t)(l15 & 7) << 4);
      bfrag[ni] = *(const s16x8*)((const char*)ot + byte);
    }
#pragma unroll
    for (int mi = 0; mi < 2; ++mi)
#pragma unroll
      for (int ni = 0; ni < 4; ++ni)
        acc2[mi][ni] = __builtin_amdgcn_mfma_f32_16x16x32_bf16(af[mi], bfrag[ni], acc2[mi][ni], 0, 0, 0);
  }

#pragma unroll
  for (int mi = 0; mi < 2; ++mi) {
    const int oc = h * 32 + 16 * mi + 4 * l4;
    float4 bb = *(const float4*)(bias + oc);
#pragma unroll
    for (int ni = 0; ni < 4; ++ni) {
      float4 st;
      st.x = acc2[mi][ni][0] + bb.x;
      st.y = acc2[mi][ni][1] + bb.y;
      st.z = acc2[mi][ni][2] + bb.z;
      st.w = acc2[mi][ni][3] + bb.w;
      *(float4*)(out + (size_t)(g * 64 + 16 * ni + l15) * 256 + oc) = st;
    }
  }
}

extern "C" void kernel_launch(void* const* d_in, const int* in_sizes, int n_in,
                              void* d_out, int out_size, void* d_ws, size_t ws_size,
                              hipStream_t stream) {
  const float* x    = (const float*)d_in[0];
  const float* wqkv = (const float*)d_in[1];
  const float* wout = (const float*)d_in[2];
  const float* bout = (const float*)d_in[3];
  float* out = (float*)d_out;

  unsigned short* wq_bf = (unsigned short*)d_ws;          // 768*256 bf16
  unsigned short* wo_bf = wq_bf + 768 * 256;              // 256*256 bf16
  unsigned short* v_buf = wo_bf + 256 * 256;              // 2048 groups * 32KB

  convert_w<<<1024, 256, 0, stream>>>(wqkv, wout, wq_bf);
  qkv_gemm<<<6144, 256, 0, stream>>>(x, wq_bf, (unsigned short*)d_out, v_buf);
  attn_proj<<<2048, 512, 0, stream>>>((const unsigned short*)d_out, v_buf, wo_bf, bout, out);
}

// Round 10
// 269.361 us; speedup vs baseline: 1.0868x; 1.0868x over previous
//
#include <hip/hip_runtime.h>
#include <hip/hip_bf16.h>
#include <stdint.h>

typedef __attribute__((ext_vector_type(8))) short s16x8;
typedef __attribute__((ext_vector_type(4))) float f32x4;

__device__ __forceinline__ unsigned short f32_bf16(float f) {
  union { float f; uint32_t u; } v; v.f = f;
  return (unsigned short)((v.u + 0x7FFFu + ((v.u >> 16) & 1u)) >> 16);
}

__device__ __forceinline__ uint32_t pack_bf16(float lo, float hi) {
  __hip_bfloat162 h = __float22bfloat162_rn(float2{lo, hi});
  union { __hip_bfloat162 h; uint32_t u; } u; u.h = h; return u.u;
}

// Exchange 4-row chunks across the four 16-lane groups to build an MFMA
// A-fragment (k = 8*l4 + j) from C-fragment-resident data (lane = row).
__device__ __forceinline__ s16x8 xchg(uint32_t lo0, uint32_t lo1,
                                      uint32_t hi0, uint32_t hi1,
                                      int srcA, int srcB, uint32_t hisel) {
  int a0 = __shfl((int)lo0, srcA), b0 = __shfl((int)hi0, srcA);
  int a1 = __shfl((int)lo1, srcA), b1 = __shfl((int)hi1, srcA);
  int a2 = __shfl((int)lo0, srcB), b2 = __shfl((int)hi0, srcB);
  int a3 = __shfl((int)lo1, srcB), b3 = __shfl((int)hi1, srcB);
  union { uint32_t u[4]; s16x8 v; } r;
  r.u[0] = hisel ? (uint32_t)b0 : (uint32_t)a0;
  r.u[1] = hisel ? (uint32_t)b1 : (uint32_t)a1;
  r.u[2] = hisel ? (uint32_t)b2 : (uint32_t)a2;
  r.u[3] = hisel ? (uint32_t)b3 : (uint32_t)a3;
  return r.v;
}

// ---------------- kernel 1: weights f32 -> bf16 ----------------
__global__ void convert_w(const float* __restrict__ wqkv,
                          const float* __restrict__ wout,
                          unsigned short* __restrict__ o) {
  int i = blockIdx.x * 256 + threadIdx.x;           // 262144 total
  if (i < 768 * 256) o[i] = f32_bf16(wqkv[i]);
  else               o[i] = f32_bf16(wout[i - 768 * 256]);
}

// -------- kernel 2: QKV GEMM (M=131072, N=768, K=256), swapped-C --------
// 128x128 tiles, 4 waves (2x2), BK=64, reg-staged swizzled LDS.
// XCD-chunked bijective swizzle (T1): hw sends id%8 -> XCD id%8 in order,
// so orig = (id&7)*768 + (id>>3) makes each XCD process a contiguous range
// of (bm,bn) ids -> the 6 bn-blocks sharing an x-tile run back-to-back on
// the SAME XCD's L2 (x refetches become L2 hits, not HBM race-misses).
__global__ __launch_bounds__(256) void qkv_gemm(
    const float* __restrict__ x,           // [131072][256] f32
    const unsigned short* __restrict__ wq, // [768][256] bf16
    unsigned short* qk_out,                // d_out: per group 64KB {q 32K | k 32K}
    unsigned short* v_out) {               // ws: per group 32KB v[t64][256]
  __shared__ unsigned short As[128 * 64];
  __shared__ unsigned short Bs[128 * 64];
  const int id = blockIdx.x;                       // 6144 = 8 XCDs * 768
  const int orig = (id & 7) * 768 + (id >> 3);     // bijective XCD chunking
  const int bm = orig / 6;                         // token tile
  const int bn = orig - bm * 6;                    // weight tile
  const int tid = threadIdx.x;
  const int w = tid >> 6, lane = tid & 63;
  const int l15 = lane & 15, l4 = lane >> 4;
  const int wr = w >> 1, wc = w & 1;

  f32x4 acc[4][4];
#pragma unroll
  for (int mi = 0; mi < 4; ++mi)
#pragma unroll
    for (int ni = 0; ni < 4; ++ni) acc[mi][ni] = (f32x4){0.f, 0.f, 0.f, 0.f};

  const int srow = tid >> 1;
  const int sc0  = (tid & 1) * 32;
  const float* ga = x + (size_t)(bm * 128 + srow) * 256 + sc0;
  const unsigned short* gb = wq + (size_t)(bn * 128 + srow) * 256 + sc0;
  const uint32_t sbyte0 = (uint32_t)(srow * 128 + sc0 * 2);
  const uint32_t ssw = (uint32_t)(srow & 7) << 4;

  for (int kk = 0; kk < 4; ++kk) {
#pragma unroll
    for (int c = 0; c < 32; c += 8) {
      float4 f0 = *(const float4*)(ga + kk * 64 + c);
      float4 f1 = *(const float4*)(ga + kk * 64 + c + 4);
      uint4 vb = *(const uint4*)(gb + kk * 64 + c);
      uint32_t byte = (sbyte0 + c * 2) ^ ssw;
      *(uint4*)((char*)As + byte) =
          make_uint4(pack_bf16(f0.x, f0.y), pack_bf16(f0.z, f0.w),
                     pack_bf16(f1.x, f1.y), pack_bf16(f1.z, f1.w));
      *(uint4*)((char*)Bs + byte) = vb;
    }
    __syncthreads();
#pragma unroll
    for (int k2 = 0; k2 < 2; ++k2) {
      s16x8 af[4], bf[4];
#pragma unroll
      for (int mi = 0; mi < 4; ++mi) {
        int row = wr * 64 + 16 * mi + l15;
        uint32_t byte = (uint32_t)(row * 128 + k2 * 64 + l4 * 16) ^ ((row & 7) << 4);
        af[mi] = *(const s16x8*)((const char*)Bs + byte);   // w rows (A-op)
      }
#pragma unroll
      for (int ni = 0; ni < 4; ++ni) {
        int row = wc * 64 + 16 * ni + l15;
        uint32_t byte = (uint32_t)(row * 128 + k2 * 64 + l4 * 16) ^ ((row & 7) << 4);
        bf[ni] = *(const s16x8*)((const char*)As + byte);   // x rows (B-op)
      }
#pragma unroll
      for (int mi = 0; mi < 4; ++mi)
#pragma unroll
        for (int ni = 0; ni < 4; ++ni)
          acc[mi][ni] = __builtin_amdgcn_mfma_f32_16x16x32_bf16(af[mi], bf[ni], acc[mi][ni], 0, 0, 0);
    }
    __syncthreads();
  }

  // C[wcol][tok]: g = bm*2 + wc, t64 = 16ni + l15, wcol = bn*128+wr*64+16mi+4*l4+r
  const int g = bm * 2 + wc;
  if (bn < 4) {
    char* base = (char*)qk_out + ((size_t)g << 16) + ((bn & 2) ? 32768 : 0);
    const int colb = (bn & 1) * 128 + wr * 64 + 4 * l4;
#pragma unroll
    for (int mi = 0; mi < 4; ++mi)
#pragma unroll
      for (int ni = 0; ni < 4; ++ni) {
        uint2 st = make_uint2(pack_bf16(acc[mi][ni][0], acc[mi][ni][1]),
                              pack_bf16(acc[mi][ni][2], acc[mi][ni][3]));
        *(uint2*)(base + (16 * ni + l15) * 512 + (colb + 16 * mi) * 2) = st;
      }
  } else {
    char* base = (char*)v_out + ((size_t)g << 15);
    const int colb = (bn - 4) * 128 + wr * 64 + 4 * l4;
#pragma unroll
    for (int mi = 0; mi < 4; ++mi)
#pragma unroll
      for (int ni = 0; ni < 4; ++ni) {
        uint2 st = make_uint2(pack_bf16(acc[mi][ni][0], acc[mi][ni][1]),
                              pack_bf16(acc[mi][ni][2], acc[mi][ni][3]));
        *(uint2*)(base + (16 * ni + l15) * 512 + (colb + 16 * mi) * 2) = st;
      }
  }
}

// -------- kernel 3: attention + out-projection, block per group ---------
// (verbatim — runs near its HBM traffic floor)
__global__ __launch_bounds__(512) void attn_proj(
    const unsigned short* qk,              // d_out scratch (aliases out!)
    const unsigned short* __restrict__ v_buf,
    const unsigned short* __restrict__ wo, // [256][256] bf16
    const float* __restrict__ bias,
    float* out) {
  __shared__ unsigned short ot[64 * 256];  // 32 KB attn-out tile, swz rows

  const int g    = blockIdx.x;
  const int tid  = threadIdx.x;
  const int h    = tid >> 6;
  const int lane = tid & 63;
  const int l15  = lane & 15;
  const int l4   = lane >> 4;
  const int      srcA  = l15 + ((lane & 16) << 1);
  const int      srcB  = srcA + 16;
  const uint32_t hisel = (uint32_t)(lane & 32);

  const char* qbase = (const char*)qk + ((size_t)g << 16);
  const int hcolb = (h * 32 + l4 * 8) * 2;

  // ---- load q,k fragments (b128 global) ----
  s16x8 kA[4], qB[4];
#pragma unroll
  for (int mb = 0; mb < 4; ++mb)
    kA[mb] = *(const s16x8*)(qbase + 32768 + (16 * mb + l15) * 512 + hcolb);
#pragma unroll
  for (int nb = 0; nb < 4; ++nb)
    qB[nb] = *(const s16x8*)(qbase + (16 * nb + l15) * 512 + hcolb);

  // ---- load v fragments (scalar u16, B-frag: lane=d col, k=ktok) ----
  s16x8 vB[2][2];
  const char* vb0 = (const char*)v_buf + ((size_t)g << 15);
#pragma unroll
  for (int kk2 = 0; kk2 < 2; ++kk2)
#pragma unroll
    for (int t = 0; t < 2; ++t) {
      union { unsigned short u[8]; s16x8 v; } uv;
      const char* vp = vb0 + (kk2 * 32 + 8 * l4) * 512 + (h * 32 + 16 * t + l15) * 2;
#pragma unroll
      for (int j = 0; j < 8; ++j)
        uv.u[j] = *(const unsigned short*)(vp + j * 512);
      vB[kk2][t] = uv.v;
    }

  // ---- per q-block: energy^T -> softmax -> PV -> LDS store ----
#pragma unroll
  for (int nb = 0; nb < 4; ++nb) {
    f32x4 en[4];
#pragma unroll
    for (int mb = 0; mb < 4; ++mb) {
      en[mb] = (f32x4){0.f, 0.f, 0.f, 0.f};
      en[mb] = __builtin_amdgcn_mfma_f32_16x16x32_bf16(kA[mb], qB[nb], en[mb], 0, 0, 0);
    }
    float mx = en[0][0];
#pragma unroll
    for (int mb = 0; mb < 4; ++mb)
#pragma unroll
      for (int r = 0; r < 4; ++r) mx = fmaxf(mx, en[mb][r]);
    mx = fmaxf(mx, __shfl_xor(mx, 16));
    mx = fmaxf(mx, __shfl_xor(mx, 32));
    float p[4][4];
    float sum = 0.f;
#pragma unroll
    for (int mb = 0; mb < 4; ++mb)
#pragma unroll
      for (int r = 0; r < 4; ++r) {
        float t = __expf((en[mb][r] - mx) * 0.0625f);  // scale 1/sqrt(256)
        p[mb][r] = t;
        sum += t;
      }
    sum += __shfl_xor(sum, 16);
    sum += __shfl_xor(sum, 32);
    float rs = 1.0f / sum;
    uint32_t pk[4][2];
#pragma unroll
    for (int mb = 0; mb < 4; ++mb) {
      pk[mb][0] = pack_bf16(p[mb][0] * rs, p[mb][1] * rs);
      pk[mb][1] = pack_bf16(p[mb][2] * rs, p[mb][3] * rs);
    }
    f32x4 o0 = (f32x4){0.f, 0.f, 0.f, 0.f};
    f32x4 o1 = (f32x4){0.f, 0.f, 0.f, 0.f};
#pragma unroll
    for (int kk2 = 0; kk2 < 2; ++kk2) {
      s16x8 pA = xchg(pk[2 * kk2][0], pk[2 * kk2][1],
                      pk[2 * kk2 + 1][0], pk[2 * kk2 + 1][1], srcA, srcB, hisel);
      o0 = __builtin_amdgcn_mfma_f32_16x16x32_bf16(pA, vB[kk2][0], o0, 0, 0, 0);
      o1 = __builtin_amdgcn_mfma_f32_16x16x32_bf16(pA, vB[kk2][1], o1, 0, 0, 0);
    }
#pragma unroll
    for (int r = 0; r < 4; ++r) {
      int row = 16 * nb + 4 * l4 + r;
      uint32_t rsw = (uint32_t)(row & 7) << 4;
      uint32_t c0 = ((uint32_t)(row * 512 + (h * 32 + l15) * 2)) ^ rsw;
      uint32_t c1 = ((uint32_t)(row * 512 + (h * 32 + 16 + l15) * 2)) ^ rsw;
      *(unsigned short*)((char*)ot + c0) = f32_bf16(o0[r]);
      *(unsigned short*)((char*)ot + c1) = f32_bf16(o1[r]);
    }
  }
  __syncthreads();

  // ---- projection: wave h -> out cols [h*32, h*32+32), swapped C ----
  f32x4 acc2[2][4];
#pragma unroll
  for (int mi = 0; mi < 2; ++mi)
#pragma unroll
    for (int ni = 0; ni < 4; ++ni) acc2[mi][ni] = (f32x4){0.f, 0.f, 0.f, 0.f};

#pragma unroll
  for (int kk = 0; kk < 8; ++kk) {
    s16x8 af[2], bfrag[4];
#pragma unroll
    for (int mi = 0; mi < 2; ++mi)
      af[mi] = *(const s16x8*)(wo + (size_t)(h * 32 + 16 * mi + l15) * 256 + kk * 32 + l4 * 8);
#pragma unroll
    for (int ni = 0; ni < 4; ++ni) {
      uint32_t byte = ((uint32_t)((16 * ni + l15) * 512 + (kk * 32 + l4 * 8) * 2)) ^ ((uint32_t)(l15 & 7) << 4);
      bfrag[ni] = *(const s16x8*)((const char*)ot + byte);
    }
#pragma unroll
    for (int mi = 0; mi < 2; ++mi)
#pragma unroll
      for (int ni = 0; ni < 4; ++ni)
        acc2[mi][ni] = __builtin_amdgcn_mfma_f32_16x16x32_bf16(af[mi], bfrag[ni], acc2[mi][ni], 0, 0, 0);
  }

#pragma unroll
  for (int mi = 0; mi < 2; ++mi) {
    const int oc = h * 32 + 16 * mi + 4 * l4;
    float4 bb = *(const float4*)(bias + oc);
#pragma unroll
    for (int ni = 0; ni < 4; ++ni) {
      float4 st;
      st.x = acc2[mi][ni][0] + bb.x;
      st.y = acc2[mi][ni][1] + bb.y;
      st.z = acc2[mi][ni][2] + bb.z;
      st.w = acc2[mi][ni][3] + bb.w;
      *(float4*)(out + (size_t)(g * 64 + 16 * ni + l15) * 256 + oc) = st;
    }
  }
}

extern "C" void kernel_launch(void* const* d_in, const int* in_sizes, int n_in,
                              void* d_out, int out_size, void* d_ws, size_t ws_size,
                              hipStream_t stream) {
  const float* x    = (const float*)d_in[0];
  const float* wqkv = (const float*)d_in[1];
  const float* wout = (const float*)d_in[2];
  const float* bout = (const float*)d_in[3];
  float* out = (float*)d_out;

  unsigned short* wq_bf = (unsigned short*)d_ws;          // 768*256 bf16
  unsigned short* wo_bf = wq_bf + 768 * 256;              // 256*256 bf16
  unsigned short* v_buf = wo_bf + 256 * 256;              // 2048 groups * 32KB

  convert_w<<<1024, 256, 0, stream>>>(wqkv, wout, wq_bf);
  qkv_gemm<<<6144, 256, 0, stream>>>(x, wq_bf, (unsigned short*)d_out, v_buf);
  attn_proj<<<2048, 512, 0, stream>>>((const unsigned short*)d_out, v_buf, wo_bf, bout, out);
}

// Round 11
// 212.045 us; speedup vs baseline: 1.3806x; 1.2703x over previous
//
#include <hip/hip_runtime.h>
#include <hip/hip_bf16.h>
#include <stdint.h>

typedef __attribute__((ext_vector_type(8))) short s16x8;
typedef __attribute__((ext_vector_type(4))) float f32x4;

#define GLDS(gp, lp) __builtin_amdgcn_global_load_lds(                      \
    (const __attribute__((address_space(1))) void*)(gp),                    \
    (__attribute__((address_space(3))) void*)(lp), 16, 0, 0)

__device__ __forceinline__ unsigned short f32_bf16(float f) {
  union { float f; uint32_t u; } v; v.f = f;
  return (unsigned short)((v.u + 0x7FFFu + ((v.u >> 16) & 1u)) >> 16);
}

__device__ __forceinline__ uint32_t pack_bf16(float lo, float hi) {
  __hip_bfloat162 h = __float22bfloat162_rn(float2{lo, hi});
  union { __hip_bfloat162 h; uint32_t u; } u; u.h = h; return u.u;
}

// Exchange 4-row chunks across the four 16-lane groups to build an MFMA
// A-fragment (k = 8*l4 + j) from C-fragment-resident data (lane = row).
__device__ __forceinline__ s16x8 xchg(uint32_t lo0, uint32_t lo1,
                                      uint32_t hi0, uint32_t hi1,
                                      int srcA, int srcB, uint32_t hisel) {
  int a0 = __shfl((int)lo0, srcA), b0 = __shfl((int)hi0, srcA);
  int a1 = __shfl((int)lo1, srcA), b1 = __shfl((int)hi1, srcA);
  int a2 = __shfl((int)lo0, srcB), b2 = __shfl((int)hi0, srcB);
  int a3 = __shfl((int)lo1, srcB), b3 = __shfl((int)hi1, srcB);
  union { uint32_t u[4]; s16x8 v; } r;
  r.u[0] = hisel ? (uint32_t)b0 : (uint32_t)a0;
  r.u[1] = hisel ? (uint32_t)b1 : (uint32_t)a1;
  r.u[2] = hisel ? (uint32_t)b2 : (uint32_t)a2;
  r.u[3] = hisel ? (uint32_t)b3 : (uint32_t)a3;
  return r.v;
}

// ---------------- kernel 1: weights f32 -> bf16 ----------------
__global__ void convert_w(const float* __restrict__ wqkv,
                          const float* __restrict__ wout,
                          unsigned short* __restrict__ o) {
  int i = blockIdx.x * 256 + threadIdx.x;           // 262144 total
  if (i < 768 * 256) o[i] = f32_bf16(wqkv[i]);
  else               o[i] = f32_bf16(wout[i - 768 * 256]);
}

// -------- kernel 2: QKV GEMM (M=131072, N=768, K=256), swapped-C --------
// m97-style async staging: global_load_lds(16B) DMA for BOTH tiles, with
// pre-swizzled per-lane SOURCE addresses (linear LDS dest) so swizzled
// ds_read_b128 fragment reads are bank-conflict-free. x stays f32 in LDS;
// f32->bf16 happens at fragment-read via cvt_pk (compiler-generated).
// XCD-chunked bijective blockIdx swizzle (validated R10: FETCH 421->67MB).
__global__ __launch_bounds__(256) void qkv_gemm(
    const float* __restrict__ x,           // [131072][256] f32
    const unsigned short* __restrict__ wq, // [768][256] bf16
    unsigned short* qk_out,                // d_out: per group 64KB {q 32K | k 32K}
    unsigned short* v_out) {               // ws: per group 32KB v[t64][256]
  __shared__ float          As[128 * 64];          // 32 KB f32 x tile
  __shared__ unsigned short Bs[128 * 64];          // 16 KB bf16 w tile
  const int id = blockIdx.x;                       // 6144 = 8 XCDs * 768
  const int orig = (id & 7) * 768 + (id >> 3);     // bijective XCD chunking
  const int bm = orig / 6;                         // token tile
  const int bn = orig - bm * 6;                    // weight tile
  const int tid = threadIdx.x;
  const int w = tid >> 6, lane = tid & 63;
  const int l15 = lane & 15, l4 = lane >> 4;
  const int wr = w >> 1, wc = w & 1;

  f32x4 acc[4][4];
#pragma unroll
  for (int mi = 0; mi < 4; ++mi)
#pragma unroll
    for (int ni = 0; ni < 4; ++ni) acc[mi][ni] = (f32x4){0.f, 0.f, 0.f, 0.f};

  // staging geometry (per wave): A rows [w*32,+32) in 8 pkts of 4 rows;
  // B rows [w*32,+32) in 4 pkts of 8 rows. HW writes lds_base + lane*16.
  const int arow0 = w * 32 + (lane >> 4);   // + j*4
  const int ac    = lane & 15;              // 16B granule in 256B row
  const int brow0 = w * 32 + (lane >> 3);   // + j*8
  const int bc    = lane & 7;               // 16B granule in 128B row

#pragma unroll
  for (int kk = 0; kk < 4; ++kk) {
    // ---- async stage A (x, f32): 8 DMA / thread ----
#pragma unroll
    for (int j = 0; j < 8; ++j) {
      int row = arow0 + j * 4;
      const float* src = x + (size_t)(bm * 128 + row) * 256 + kk * 64
                         + ((ac ^ (row & 7)) << 2);
      GLDS(src, (char*)As + (size_t)(w * 32 + j * 4) * 256);
    }
    // ---- async stage B (w, bf16): 4 DMA / thread ----
#pragma unroll
    for (int j = 0; j < 4; ++j) {
      int row = brow0 + j * 8;
      const unsigned short* src = wq + (size_t)(bn * 128 + row) * 256 + kk * 64
                                  + ((bc ^ (row & 7)) << 3);
      GLDS(src, (char*)Bs + (size_t)(w * 32 + j * 8) * 128);
    }
    __syncthreads();   // drains vmcnt -> staged data visible

#pragma unroll
    for (int k2 = 0; k2 < 2; ++k2) {
      s16x8 af[4], bf[4];
#pragma unroll
      for (int mi = 0; mi < 4; ++mi) {
        int row = wr * 64 + 16 * mi + l15;
        int gr = (k2 * 4 + l4) ^ (row & 7);
        af[mi] = *(const s16x8*)((const char*)Bs + row * 128 + gr * 16);
      }
#pragma unroll
      for (int ni = 0; ni < 4; ++ni) {
        int row = wc * 64 + 16 * ni + l15;
        int g0 = (k2 * 8 + l4 * 2) ^ (row & 7);
        int g1 = (k2 * 8 + l4 * 2 + 1) ^ (row & 7);
        float4 xa = *(const float4*)((const char*)As + row * 256 + g0 * 16);
        float4 xb = *(const float4*)((const char*)As + row * 256 + g1 * 16);
        union { uint32_t u[4]; s16x8 v; } r;
        r.u[0] = pack_bf16(xa.x, xa.y);
        r.u[1] = pack_bf16(xa.z, xa.w);
        r.u[2] = pack_bf16(xb.x, xb.y);
        r.u[3] = pack_bf16(xb.z, xb.w);
        bf[ni] = r.v;
      }
#pragma unroll
      for (int mi = 0; mi < 4; ++mi)
#pragma unroll
        for (int ni = 0; ni < 4; ++ni)
          acc[mi][ni] = __builtin_amdgcn_mfma_f32_16x16x32_bf16(af[mi], bf[ni], acc[mi][ni], 0, 0, 0);
    }
    __syncthreads();
  }

  // C[wcol][tok]: g = bm*2 + wc, t64 = 16ni + l15, wcol = bn*128+wr*64+16mi+4*l4+r
  const int g = bm * 2 + wc;
  if (bn < 4) {
    char* base = (char*)qk_out + ((size_t)g << 16) + ((bn & 2) ? 32768 : 0);
    const int colb = (bn & 1) * 128 + wr * 64 + 4 * l4;
#pragma unroll
    for (int mi = 0; mi < 4; ++mi)
#pragma unroll
      for (int ni = 0; ni < 4; ++ni) {
        uint2 st = make_uint2(pack_bf16(acc[mi][ni][0], acc[mi][ni][1]),
                              pack_bf16(acc[mi][ni][2], acc[mi][ni][3]));
        *(uint2*)(base + (16 * ni + l15) * 512 + (colb + 16 * mi) * 2) = st;
      }
  } else {
    char* base = (char*)v_out + ((size_t)g << 15);
    const int colb = (bn - 4) * 128 + wr * 64 + 4 * l4;
#pragma unroll
    for (int mi = 0; mi < 4; ++mi)
#pragma unroll
      for (int ni = 0; ni < 4; ++ni) {
        uint2 st = make_uint2(pack_bf16(acc[mi][ni][0], acc[mi][ni][1]),
                              pack_bf16(acc[mi][ni][2], acc[mi][ni][3]));
        *(uint2*)(base + (16 * ni + l15) * 512 + (colb + 16 * mi) * 2) = st;
      }
  }
}

// -------- kernel 3: attention + out-projection, block per group ---------
// (verbatim — runs near its HBM traffic floor)
__global__ __launch_bounds__(512) void attn_proj(
    const unsigned short* qk,              // d_out scratch (aliases out!)
    const unsigned short* __restrict__ v_buf,
    const unsigned short* __restrict__ wo, // [256][256] bf16
    const float* __restrict__ bias,
    float* out) {
  __shared__ unsigned short ot[64 * 256];  // 32 KB attn-out tile, swz rows

  const int g    = blockIdx.x;
  const int tid  = threadIdx.x;
  const int h    = tid >> 6;
  const int lane = tid & 63;
  const int l15  = lane & 15;
  const int l4   = lane >> 4;
  const int      srcA  = l15 + ((lane & 16) << 1);
  const int      srcB  = srcA + 16;
  const uint32_t hisel = (uint32_t)(lane & 32);

  const char* qbase = (const char*)qk + ((size_t)g << 16);
  const int hcolb = (h * 32 + l4 * 8) * 2;

  // ---- load q,k fragments (b128 global) ----
  s16x8 kA[4], qB[4];
#pragma unroll
  for (int mb = 0; mb < 4; ++mb)
    kA[mb] = *(const s16x8*)(qbase + 32768 + (16 * mb + l15) * 512 + hcolb);
#pragma unroll
  for (int nb = 0; nb < 4; ++nb)
    qB[nb] = *(const s16x8*)(qbase + (16 * nb + l15) * 512 + hcolb);

  // ---- load v fragments (scalar u16, B-frag: lane=d col, k=ktok) ----
  s16x8 vB[2][2];
  const char* vb0 = (const char*)v_buf + ((size_t)g << 15);
#pragma unroll
  for (int kk2 = 0; kk2 < 2; ++kk2)
#pragma unroll
    for (int t = 0; t < 2; ++t) {
      union { unsigned short u[8]; s16x8 v; } uv;
      const char* vp = vb0 + (kk2 * 32 + 8 * l4) * 512 + (h * 32 + 16 * t + l15) * 2;
#pragma unroll
      for (int j = 0; j < 8; ++j)
        uv.u[j] = *(const unsigned short*)(vp + j * 512);
      vB[kk2][t] = uv.v;
    }

  // ---- per q-block: energy^T -> softmax -> PV -> LDS store ----
#pragma unroll
  for (int nb = 0; nb < 4; ++nb) {
    f32x4 en[4];
#pragma unroll
    for (int mb = 0; mb < 4; ++mb) {
      en[mb] = (f32x4){0.f, 0.f, 0.f, 0.f};
      en[mb] = __builtin_amdgcn_mfma_f32_16x16x32_bf16(kA[mb], qB[nb], en[mb], 0, 0, 0);
    }
    float mx = en[0][0];
#pragma unroll
    for (int mb = 0; mb < 4; ++mb)
#pragma unroll
      for (int r = 0; r < 4; ++r) mx = fmaxf(mx, en[mb][r]);
    mx = fmaxf(mx, __shfl_xor(mx, 16));
    mx = fmaxf(mx, __shfl_xor(mx, 32));
    float p[4][4];
    float sum = 0.f;
#pragma unroll
    for (int mb = 0; mb < 4; ++mb)
#pragma unroll
      for (int r = 0; r < 4; ++r) {
        float t = __expf((en[mb][r] - mx) * 0.0625f);  // scale 1/sqrt(256)
        p[mb][r] = t;
        sum += t;
      }
    sum += __shfl_xor(sum, 16);
    sum += __shfl_xor(sum, 32);
    float rs = 1.0f / sum;
    uint32_t pk[4][2];
#pragma unroll
    for (int mb = 0; mb < 4; ++mb) {
      pk[mb][0] = pack_bf16(p[mb][0] * rs, p[mb][1] * rs);
      pk[mb][1] = pack_bf16(p[mb][2] * rs, p[mb][3] * rs);
    }
    f32x4 o0 = (f32x4){0.f, 0.f, 0.f, 0.f};
    f32x4 o1 = (f32x4){0.f, 0.f, 0.f, 0.f};
#pragma unroll
    for (int kk2 = 0; kk2 < 2; ++kk2) {
      s16x8 pA = xchg(pk[2 * kk2][0], pk[2 * kk2][1],
                      pk[2 * kk2 + 1][0], pk[2 * kk2 + 1][1], srcA, srcB, hisel);
      o0 = __builtin_amdgcn_mfma_f32_16x16x32_bf16(pA, vB[kk2][0], o0, 0, 0, 0);
      o1 = __builtin_amdgcn_mfma_f32_16x16x32_bf16(pA, vB[kk2][1], o1, 0, 0, 0);
    }
#pragma unroll
    for (int r = 0; r < 4; ++r) {
      int row = 16 * nb + 4 * l4 + r;
      uint32_t rsw = (uint32_t)(row & 7) << 4;
      uint32_t c0 = ((uint32_t)(row * 512 + (h * 32 + l15) * 2)) ^ rsw;
      uint32_t c1 = ((uint32_t)(row * 512 + (h * 32 + 16 + l15) * 2)) ^ rsw;
      *(unsigned short*)((char*)ot + c0) = f32_bf16(o0[r]);
      *(unsigned short*)((char*)ot + c1) = f32_bf16(o1[r]);
    }
  }
  __syncthreads();

  // ---- projection: wave h -> out cols [h*32, h*32+32), swapped C ----
  f32x4 acc2[2][4];
#pragma unroll
  for (int mi = 0; mi < 2; ++mi)
#pragma unroll
    for (int ni = 0; ni < 4; ++ni) acc2[mi][ni] = (f32x4){0.f, 0.f, 0.f, 0.f};

#pragma unroll
  for (int kk = 0; kk < 8; ++kk) {
    s16x8 af[2], bfrag[4];
#pragma unroll
    for (int mi = 0; mi < 2; ++mi)
      af[mi] = *(const s16x8*)(wo + (size_t)(h * 32 + 16 * mi + l15) * 256 + kk * 32 + l4 * 8);
#pragma unroll
    for (int ni = 0; ni < 4; ++ni) {
      uint32_t byte = ((uint32_t)((16 * ni + l15) * 512 + (kk * 32 + l4 * 8) * 2)) ^ ((uint32_t)(l15 & 7) << 4);
      bfrag[ni] = *(const s16x8*)((const char*)ot + byte);
    }
#pragma unroll
    for (int mi = 0; mi < 2; ++mi)
#pragma unroll
      for (int ni = 0; ni < 4; ++ni)
        acc2[mi][ni] = __builtin_amdgcn_mfma_f32_16x16x32_bf16(af[mi], bfrag[ni], acc2[mi][ni], 0, 0, 0);
  }

#pragma unroll
  for (int mi = 0; mi < 2; ++mi) {
    const int oc = h * 32 + 16 * mi + 4 * l4;
    float4 bb = *(const float4*)(bias + oc);
#pragma unroll
    for (int ni = 0; ni < 4; ++ni) {
      float4 st;
      st.x = acc2[mi][ni][0] + bb.x;
      st.y = acc2[mi][ni][1] + bb.y;
      st.z = acc2[mi][ni][2] + bb.z;
      st.w = acc2[mi][ni][3] + bb.w;
      *(float4*)(out + (size_t)(g * 64 + 16 * ni + l15) * 256 + oc) = st;
    }
  }
}

extern "C" void kernel_launch(void* const* d_in, const int* in_sizes, int n_in,
                              void* d_out, int out_size, void* d_ws, size_t ws_size,
                              hipStream_t stream) {
  const float* x    = (const float*)d_in[0];
  const float* wqkv = (const float*)d_in[1];
  const float* wout = (const float*)d_in[2];
  const float* bout = (const float*)d_in[3];
  float* out = (float*)d_out;

  unsigned short* wq_bf = (unsigned short*)d_ws;          // 768*256 bf16
  unsigned short* wo_bf = wq_bf + 768 * 256;              // 256*256 bf16
  unsigned short* v_buf = wo_bf + 256 * 256;              // 2048 groups * 32KB

  convert_w<<<1024, 256, 0, stream>>>(wqkv, wout, wq_bf);
  qkv_gemm<<<6144, 256, 0, stream>>>(x, wq_bf, (unsigned short*)d_out, v_buf);
  attn_proj<<<2048, 512, 0, stream>>>((const unsigned short*)d_out, v_buf, wo_bf, bout, out);
}